// Round 18
// baseline (2236.830 us; speedup 1.0000x reference)
//
#include <hip/hip_runtime.h>

#define TT 1024
#define BB 64
#define FF 256
#define HH 512
#define HPAD 544   // batch stride in shorts: 1088B == 64B mod 128B -> bank-free A-reads

typedef short bf16x8 __attribute__((ext_vector_type(8)));
typedef float f32x4  __attribute__((ext_vector_type(4)));

// ---------------------------------------------------------------------------
// Kernel 1: i_n = x @ W_ih^T + b_ih  -> io (= d_out).  (unchanged)
// ---------------------------------------------------------------------------
__global__ __launch_bounds__(256) void in_gemm(
    const float* __restrict__ x, const float* __restrict__ Wih,
    const float* __restrict__ bih, float* __restrict__ io)
{
    __shared__ float xs[32][68];
    __shared__ float wst[64][68];

    const int bid = blockIdx.x;
    const int rb = bid >> 3, cb = bid & 7;
    const int m0 = rb * 32, n0 = cb * 64;
    const int t  = threadIdx.x;
    const int ti = t >> 4, tj = t & 15;

    float acc[2][4] = {{0.f,0.f,0.f,0.f},{0.f,0.f,0.f,0.f}};

    for (int k0 = 0; k0 < FF; k0 += 64) {
        {
            int flat = t * 8;
            int row = flat >> 6, col = flat & 63;
            const float* src = &x[(size_t)(m0 + row) * FF + k0 + col];
            float4 a = *(const float4*)&src[0];
            float4 b = *(const float4*)&src[4];
            *(float4*)&xs[row][col]     = a;
            *(float4*)&xs[row][col + 4] = b;
        }
        {
            int j  = t >> 2;
            int kk = (t & 3) * 16;
            const float* src = &Wih[(size_t)(n0 + j) * FF + k0 + kk];
            #pragma unroll
            for (int q = 0; q < 4; ++q) {
                float4 v = *(const float4*)&src[q * 4];
                wst[kk + q*4 + 0][j] = v.x;
                wst[kk + q*4 + 1][j] = v.y;
                wst[kk + q*4 + 2][j] = v.z;
                wst[kk + q*4 + 3][j] = v.w;
            }
        }
        __syncthreads();
        #pragma unroll
        for (int k = 0; k < 64; k += 4) {
            float4 xa = *(const float4*)&xs[ti][k];
            float4 xb = *(const float4*)&xs[ti + 16][k];
            #pragma unroll
            for (int q = 0; q < 4; ++q) {
                float4 wv = *(const float4*)&wst[k + q][tj * 4];
                float xav = (&xa.x)[q], xbv = (&xb.x)[q];
                acc[0][0] = fmaf(xav, wv.x, acc[0][0]);
                acc[0][1] = fmaf(xav, wv.y, acc[0][1]);
                acc[0][2] = fmaf(xav, wv.z, acc[0][2]);
                acc[0][3] = fmaf(xav, wv.w, acc[0][3]);
                acc[1][0] = fmaf(xbv, wv.x, acc[1][0]);
                acc[1][1] = fmaf(xbv, wv.y, acc[1][1]);
                acc[1][2] = fmaf(xbv, wv.z, acc[1][2]);
                acc[1][3] = fmaf(xbv, wv.w, acc[1][3]);
            }
        }
        __syncthreads();
    }

    float4 bv = *(const float4*)&bih[n0 + tj * 4];
    float4 r0 = make_float4(acc[0][0]+bv.x, acc[0][1]+bv.y, acc[0][2]+bv.z, acc[0][3]+bv.w);
    float4 r1 = make_float4(acc[1][0]+bv.x, acc[1][1]+bv.y, acc[1][2]+bv.z, acc[1][3]+bv.w);
    *(float4*)&io[(size_t)(m0 + ti)      * HH + n0 + tj * 4] = r0;
    *(float4*)&io[(size_t)(m0 + ti + 16) * HH + n0 + tj * 4] = r1;
}

// ---------------------------------------------------------------------------
// Kernel 2: ROUND-18 — two-group interleave on the r17 MFMA structure.
//
// r17: bank fix verified exactly (1.34e8 -> 0); step 2950cy, ~1800cy of it
// the serial publish->visible->poll->stage chain. Hide that RTT under an
// INDEPENDENT group's compute (r10's idea; its failure mode -- straggler
// concentrated epilogue -- is gone here because the epilogue is distributed
// across all waves' lanes 0-7, keeping waves lockstep).
//  * 128 WGs = 8 slices x 16; WG (s,j) owns groups j AND j+16 (same 8 WGs
//    produce+consume both -> skew bounded; ring/epoch guarantees as before).
//  * Step = phase A (group j), phase B (group j+16). Per phase: validate
//    REGISTER-HELD spec h (loaded one phase earlier, epoch self-validating;
//    miss -> r13 poll loop) -> stage -> barrier -> spec-issue the other
//    phase's loads (fly under MFMA) -> 2-chain MFMA -> distributed
//    epilogue + publish.
//  * hstA/hstB parity-buffered; HPAD bank-free layout; 2 barriers/step;
//    ~85KB LDS pad prevents 2-WG stacking.
// ---------------------------------------------------------------------------
__device__ __forceinline__ unsigned short f2bf(float x) {
    unsigned u = __float_as_uint(x);
    return (unsigned short)((u + 0x7FFFu + ((u >> 16) & 1u)) >> 16);  // RNE
}

#define PB4(i) "+v"(Bfrag[(i)+0]), "+v"(Bfrag[(i)+1]), "+v"(Bfrag[(i)+2]), "+v"(Bfrag[(i)+3])

__global__ __launch_bounds__(512, 2) void mgu_rec(
    const float* __restrict__ Whh, const float* __restrict__ bhh,
    float* __restrict__ io, float* __restrict__ hbuf)
{
    const int bid = blockIdx.x;
    const int s   = bid >> 4;     // row slice 0..7 (owns h-rows 64s..64s+64)
    const int j   = bid & 15;     // group pair index
    const int cA  = 2 * j;        // group A batches {cA, cA+1}
    const int cB  = 2 * j + 32;   // group B batches {cB, cB+1}
    const int tid = threadIdx.x;
    const int w   = tid >> 6;     // wave 0..7
    const int l   = tid & 63;
    const int n   = l & 15;       // B col within tile
    const int q   = l >> 4;       // k-subgroup

    __shared__ short hstA[2][2][HPAD];   // [parity][batch][k] bf16
    __shared__ short hstB[2][2][HPAD];
    __shared__ float lds_pad[19456];     // 76 KB -> total ~85KB => no stacking
    if (tid == 0) { volatile float* vp = lds_pad; vp[0] = 0.f; }

    // --- persistent W as B-fragments (shared by both groups) ---
    bf16x8 Bfrag[16];
    {
        const int grow = (n < 8) ? (s * 64 + 8 * w + n)
                                 : (512 + s * 64 + 8 * w + (n - 8));
        const float* src = &Whh[(size_t)grow * HH + 8 * q];
        #pragma unroll
        for (int kk = 0; kk < 16; ++kk) {
            bf16x8 f;
            #pragma unroll
            for (int jj = 0; jj < 8; ++jj)
                f[jj] = (short)f2bf(src[32 * kk + jj]);
            Bfrag[kk] = f;
        }
    }
    asm volatile("" : PB4(0), PB4(4), PB4(8), PB4(12));   // pin

    const bool epi = (l < 8);
    const int  row = s * 64 + 8 * w + l;      // valid when epi
    float bfv = 0.f, bnv = 0.f;
    float hpA0 = 0.f, hpA1 = 0.f, hpB0 = 0.f, hpB1 = 0.f;  // h_prev registers
    float icA0, icA1, icB0, icB1;                           // i_n current
    float inA0 = 0.f, inA1 = 0.f, inB0 = 0.f, inB1 = 0.f;   // i_n next
    size_t oA0 = 0, oA1 = 0, oB0 = 0, oB1 = 0;
    if (epi) {
        bfv = bhh[row];
        bnv = bhh[512 + row];
        oA0 = (size_t)(cA + 0) * HH + row;  oA1 = oA0 + HH;
        oB0 = (size_t)(cB + 0) * HH + row;  oB1 = oB0 + HH;
        inA0 = io[oA0]; inA1 = io[oA1];     // i_n for t=0
        inB0 = io[oB0]; inB1 = io[oB1];
    }

    const int kb = w * 64;          // poll/stage k-base for this wave
    float sA0 = 0.f, sA1 = 0.f;     // speculative h regs (epoch 0 = invalid)
    float sB0 = 0.f, sB1 = 0.f;

    for (int t = 0; t < TT; ++t) {
        const int par = t & 1;
        icA0 = inA0; icA1 = inA1; icB0 = inB0; icB1 = inB1;

        // ==================== PHASE A (group j) ====================
        {
            float v0, v1;
            if (t > 0) {
                const int tr = t - 1;
                const unsigned ep = (unsigned)(((tr >> 2) % 3) + 1);
                bool ok = ((__float_as_uint(sA0) & 3u) == ep) &&
                          ((__float_as_uint(sA1) & 3u) == ep);
                if (__all(ok)) { v0 = sA0; v1 = sA1; }
                else {
                    const float* b0 = &hbuf[(size_t)(tr & 3) * BB * HH
                                            + (size_t)cA * HH + kb + l];
                    const float* b1 = b0 + HH;
                    for (;;) {
                        v0 = __hip_atomic_load(b0, __ATOMIC_RELAXED, __HIP_MEMORY_SCOPE_AGENT);
                        v1 = __hip_atomic_load(b1, __ATOMIC_RELAXED, __HIP_MEMORY_SCOPE_AGENT);
                        bool k2 = ((__float_as_uint(v0) & 3u) == ep) &&
                                  ((__float_as_uint(v1) & 3u) == ep);
                        if (__all(k2)) break;
                    }
                }
            } else { v0 = 0.f; v1 = 0.f; }
            hstA[par][0][kb + l] = (short)f2bf(v0);
            hstA[par][1][kb + l] = (short)f2bf(v1);

            __syncthreads();

            // spec-issue group B's h (slot t-1) — flies under MFMA A
            if (t > 0) {
                const int tr = t - 1;
                const float* b0 = &hbuf[(size_t)(tr & 3) * BB * HH
                                        + (size_t)cB * HH + kb + l];
                sB0 = __hip_atomic_load(b0,      __ATOMIC_RELAXED, __HIP_MEMORY_SCOPE_AGENT);
                sB1 = __hip_atomic_load(b0 + HH, __ATOMIC_RELAXED, __HIP_MEMORY_SCOPE_AGENT);
            }
            // i_n prefetch for t+1 (4 streams, hidden under both phases)
            if (epi && t + 1 < TT) {
                const size_t st = (size_t)(t + 1) * BB * HH;
                inA0 = io[oA0 + st]; inA1 = io[oA1 + st];
                inB0 = io[oB0 + st]; inB1 = io[oB1 + st];
            }

            f32x4 accE = {0.f,0.f,0.f,0.f}, accO = {0.f,0.f,0.f,0.f};
            const short* abase = &hstA[par][l & 1][8 * q];
            #pragma unroll
            for (int kk = 0; kk < 8; ++kk) {
                bf16x8 aE = *(const bf16x8*)&abase[64 * kk];
                bf16x8 aO = *(const bf16x8*)&abase[64 * kk + 32];
                accE = __builtin_amdgcn_mfma_f32_16x16x32_bf16(aE, Bfrag[2*kk+0], accE, 0, 0, 0);
                accO = __builtin_amdgcn_mfma_f32_16x16x32_bf16(aO, Bfrag[2*kk+1], accO, 0, 0, 0);
            }
            const float f0 = accE[0] + accO[0];
            const float f1 = accE[1] + accO[1];
            const float o0 = __shfl_xor(f0, 8, 64);
            const float o1 = __shfl_xor(f1, 8, 64);

            if (epi) {
                float fg0 = __builtin_amdgcn_rcpf(1.f + __expf(-(f0 + bfv)));
                float e20 = __expf(2.f * (icA0 + fg0 * (o0 + bnv)));
                float nv0 = 1.f - 2.f * __builtin_amdgcn_rcpf(e20 + 1.f);
                float hn0 = nv0 + (1.f - fg0) * (hpA0 - nv0);
                float fg1 = __builtin_amdgcn_rcpf(1.f + __expf(-(f1 + bfv)));
                float e21 = __expf(2.f * (icA1 + fg1 * (o1 + bnv)));
                float nv1 = 1.f - 2.f * __builtin_amdgcn_rcpf(e21 + 1.f);
                float hn1 = nv1 + (1.f - fg1) * (hpA1 - nv1);
                hpA0 = hn0; hpA1 = hn1;

                const unsigned ep = (unsigned)(((t >> 2) % 3) + 1);
                float ev0 = __uint_as_float((__float_as_uint(hn0) & ~3u) | ep);
                float ev1 = __uint_as_float((__float_as_uint(hn1) & ~3u) | ep);
                const size_t doff = (size_t)(t & 3) * BB * HH;
                __hip_atomic_store(&hbuf[doff + oA0], ev0, __ATOMIC_RELAXED, __HIP_MEMORY_SCOPE_AGENT);
                __hip_atomic_store(&hbuf[doff + oA1], ev1, __ATOMIC_RELAXED, __HIP_MEMORY_SCOPE_AGENT);
                const size_t st = (size_t)t * BB * HH;
                io[oA0 + st] = hn0;
                io[oA1 + st] = hn1;
            }
        }

        // ==================== PHASE B (group j+16) ====================
        {
            float v0, v1;
            if (t > 0) {
                const int tr = t - 1;
                const unsigned ep = (unsigned)(((tr >> 2) % 3) + 1);
                bool ok = ((__float_as_uint(sB0) & 3u) == ep) &&
                          ((__float_as_uint(sB1) & 3u) == ep);
                if (__all(ok)) { v0 = sB0; v1 = sB1; }
                else {
                    const float* b0 = &hbuf[(size_t)(tr & 3) * BB * HH
                                            + (size_t)cB * HH + kb + l];
                    const float* b1 = b0 + HH;
                    for (;;) {
                        v0 = __hip_atomic_load(b0, __ATOMIC_RELAXED, __HIP_MEMORY_SCOPE_AGENT);
                        v1 = __hip_atomic_load(b1, __ATOMIC_RELAXED, __HIP_MEMORY_SCOPE_AGENT);
                        bool k2 = ((__float_as_uint(v0) & 3u) == ep) &&
                                  ((__float_as_uint(v1) & 3u) == ep);
                        if (__all(k2)) break;
                    }
                }
            } else { v0 = 0.f; v1 = 0.f; }
            hstB[par][0][kb + l] = (short)f2bf(v0);
            hstB[par][1][kb + l] = (short)f2bf(v1);

            __syncthreads();

            // spec-issue group A's h for NEXT step (slot t, just published)
            if (t + 1 < TT) {
                const float* b0 = &hbuf[(size_t)(t & 3) * BB * HH
                                        + (size_t)cA * HH + kb + l];
                sA0 = __hip_atomic_load(b0,      __ATOMIC_RELAXED, __HIP_MEMORY_SCOPE_AGENT);
                sA1 = __hip_atomic_load(b0 + HH, __ATOMIC_RELAXED, __HIP_MEMORY_SCOPE_AGENT);
            }

            f32x4 accE = {0.f,0.f,0.f,0.f}, accO = {0.f,0.f,0.f,0.f};
            const short* abase = &hstB[par][l & 1][8 * q];
            #pragma unroll
            for (int kk = 0; kk < 8; ++kk) {
                bf16x8 aE = *(const bf16x8*)&abase[64 * kk];
                bf16x8 aO = *(const bf16x8*)&abase[64 * kk + 32];
                accE = __builtin_amdgcn_mfma_f32_16x16x32_bf16(aE, Bfrag[2*kk+0], accE, 0, 0, 0);
                accO = __builtin_amdgcn_mfma_f32_16x16x32_bf16(aO, Bfrag[2*kk+1], accO, 0, 0, 0);
            }
            const float f0 = accE[0] + accO[0];
            const float f1 = accE[1] + accO[1];
            const float o0 = __shfl_xor(f0, 8, 64);
            const float o1 = __shfl_xor(f1, 8, 64);

            if (epi) {
                float fg0 = __builtin_amdgcn_rcpf(1.f + __expf(-(f0 + bfv)));
                float e20 = __expf(2.f * (icB0 + fg0 * (o0 + bnv)));
                float nv0 = 1.f - 2.f * __builtin_amdgcn_rcpf(e20 + 1.f);
                float hn0 = nv0 + (1.f - fg0) * (hpB0 - nv0);
                float fg1 = __builtin_amdgcn_rcpf(1.f + __expf(-(f1 + bfv)));
                float e21 = __expf(2.f * (icB1 + fg1 * (o1 + bnv)));
                float nv1 = 1.f - 2.f * __builtin_amdgcn_rcpf(e21 + 1.f);
                float hn1 = nv1 + (1.f - fg1) * (hpB1 - nv1);
                hpB0 = hn0; hpB1 = hn1;

                const unsigned ep = (unsigned)(((t >> 2) % 3) + 1);
                float ev0 = __uint_as_float((__float_as_uint(hn0) & ~3u) | ep);
                float ev1 = __uint_as_float((__float_as_uint(hn1) & ~3u) | ep);
                const size_t doff = (size_t)(t & 3) * BB * HH;
                __hip_atomic_store(&hbuf[doff + oB0], ev0, __ATOMIC_RELAXED, __HIP_MEMORY_SCOPE_AGENT);
                __hip_atomic_store(&hbuf[doff + oB1], ev1, __ATOMIC_RELAXED, __HIP_MEMORY_SCOPE_AGENT);
                const size_t st = (size_t)t * BB * HH;
                io[oB0 + st] = hn0;
                io[oB1 + st] = hn1;
            }
        }
    }
}

// ---------------------------------------------------------------------------
extern "C" void kernel_launch(void* const* d_in, const int* in_sizes, int n_in,
                              void* d_out, int out_size, void* d_ws, size_t ws_size,
                              hipStream_t stream)
{
    const float* x   = (const float*)d_in[0];
    const float* Wih = (const float*)d_in[1];
    const float* Whh = (const float*)d_in[2];
    const float* bih = (const float*)d_in[3];
    const float* bhh = (const float*)d_in[4];
    float* io = (float*)d_out;

    float* hbuf = (float*)d_ws;   // 4 slots x 64 batches x 512 f32 = 512 KB

    // zero the slot ring: epoch bits 0 never match live epochs {1,2,3};
    // re-runs every launch/replay -> deterministic.
    (void)hipMemsetAsync(d_ws, 0, 4 * BB * HH * 4, stream);

    in_gemm<<<dim3(16384), dim3(256), 0, stream>>>(x, Wih, bih, io);
    mgu_rec<<<dim3(128), dim3(512), 0, stream>>>(Whh, bhh, io, hbuf);
}

// Round 19
// 1432.669 us; speedup vs baseline: 1.5613x; 1.5613x over previous
//
#include <hip/hip_runtime.h>

#define TT 1024
#define BB 64
#define FF 256
#define HH 512
#define HPAD 544   // batch stride in shorts: 1088B == 64B mod 128B -> bank-free A-reads

typedef short bf16x8 __attribute__((ext_vector_type(8)));
typedef float f32x4  __attribute__((ext_vector_type(4)));

__device__ __forceinline__ unsigned short f2bf(float x) {
    unsigned u = __float_as_uint(x);
    return (unsigned short)((u + 0x7FFFu + ((u >> 16) & 1u)) >> 16);  // RNE
}
__device__ __forceinline__ float bf2f(unsigned short h) {
    return __uint_as_float(((unsigned)h) << 16);
}

// ---------------------------------------------------------------------------
// Kernel 1 (ROUND-19): i_n = x @ Wih^T + bih on the MATRIX pipe.
// fp32 VALU version ran ~250us (vs 110us VALU floor); MFMA is memory-bound:
// (64MB x-read + 128MB io-write)/6.3TB/s ~= 30us floor.
// Numerics: 3-product hi/lo split (x_hi*W_hi + x_lo*W_hi + x_hi*W_lo):
// residual ~ x_lo*W_lo ~= 1.6e-5 rel -> fp32-equivalent; no accuracy risk.
// Fragment mapping identical to the verified r16/r17 recurrence MFMAs:
//   A: row=l&15, k=8*(l>>4)+j ; B: col=l&15, same k ; D: col=l&15,
//   row=4*(l>>4)+reg.
// Tile: WG = 256 thr (4 waves) x (32m x 512n); wave w: n in [128w,128w+128)
// as 8 n-tiles; 2 m-tiles; K = 8 chunks of 32. 384 MFMAs/wave.
// Grid: M/32 = 2048 WGs.
// ---------------------------------------------------------------------------
__global__ __launch_bounds__(256) void in_gemm(
    const float* __restrict__ x, const float* __restrict__ Wih,
    const float* __restrict__ bih, float* __restrict__ io)
{
    const int m0   = blockIdx.x * 32;
    const int tid  = threadIdx.x;
    const int w    = tid >> 6;
    const int l    = tid & 63;
    const int rowA = l & 15;        // A-row / B-col / D-col index
    const int koff = 8 * (l >> 4);  // k-offset within each 32-chunk

    f32x4 acc[2][8];
    #pragma unroll
    for (int mt = 0; mt < 2; ++mt)
        #pragma unroll
        for (int nt = 0; nt < 8; ++nt)
            acc[mt][nt] = (f32x4){0.f, 0.f, 0.f, 0.f};

    #pragma unroll 1
    for (int kk = 0; kk < 8; ++kk) {
        // ---- A fragments (x), hi+lo ----
        bf16x8 Ahi[2], Alo[2];
        #pragma unroll
        for (int mt = 0; mt < 2; ++mt) {
            const float* ax = &x[(size_t)(m0 + mt * 16 + rowA) * FF + 32 * kk + koff];
            float4 a0 = *(const float4*)&ax[0];
            float4 a1 = *(const float4*)&ax[4];
            float av[8] = {a0.x, a0.y, a0.z, a0.w, a1.x, a1.y, a1.z, a1.w};
            bf16x8 h, lo;
            #pragma unroll
            for (int j = 0; j < 8; ++j) {
                unsigned short hb = f2bf(av[j]);
                h[j]  = (short)hb;
                lo[j] = (short)f2bf(av[j] - bf2f(hb));
            }
            Ahi[mt] = h; Alo[mt] = lo;
        }
        // ---- B fragments (Wih) per half, hi+lo; 3-product MFMA ----
        #pragma unroll
        for (int half = 0; half < 2; ++half) {
            bf16x8 Bhi[4], Blo[4];
            #pragma unroll
            for (int n4 = 0; n4 < 4; ++n4) {
                const int ncol = 128 * w + (half * 4 + n4) * 16 + rowA;
                const float* bw = &Wih[(size_t)ncol * FF + 32 * kk + koff];
                float4 b0 = *(const float4*)&bw[0];
                float4 b1 = *(const float4*)&bw[4];
                float bv[8] = {b0.x, b0.y, b0.z, b0.w, b1.x, b1.y, b1.z, b1.w};
                bf16x8 h, lo;
                #pragma unroll
                for (int j = 0; j < 8; ++j) {
                    unsigned short hb = f2bf(bv[j]);
                    h[j]  = (short)hb;
                    lo[j] = (short)f2bf(bv[j] - bf2f(hb));
                }
                Bhi[n4] = h; Blo[n4] = lo;
            }
            #pragma unroll
            for (int mt = 0; mt < 2; ++mt)
                #pragma unroll
                for (int n4 = 0; n4 < 4; ++n4) {
                    const int nt = half * 4 + n4;
                    f32x4 a = acc[mt][nt];
                    a = __builtin_amdgcn_mfma_f32_16x16x32_bf16(Ahi[mt], Bhi[n4], a, 0, 0, 0);
                    a = __builtin_amdgcn_mfma_f32_16x16x32_bf16(Alo[mt], Bhi[n4], a, 0, 0, 0);
                    a = __builtin_amdgcn_mfma_f32_16x16x32_bf16(Ahi[mt], Blo[n4], a, 0, 0, 0);
                    acc[mt][nt] = a;
                }
        }
    }

    // ---- epilogue: D col=rowA, row=4*(l>>4)+r ----
    #pragma unroll
    for (int nt = 0; nt < 8; ++nt) {
        const int col = 128 * w + nt * 16 + rowA;
        const float bv = bih[col];
        #pragma unroll
        for (int mt = 0; mt < 2; ++mt) {
            #pragma unroll
            for (int r = 0; r < 4; ++r) {
                const int row = m0 + mt * 16 + (l >> 4) * 4 + r;
                io[(size_t)row * HH + col] = acc[mt][nt][r] + bv;
            }
        }
    }
}

// ---------------------------------------------------------------------------
// Kernel 2: ROUND-17 VERBATIM (proven 1261 us; r18's 2-group interleave
// regressed -- 128 WGs idled half the chip -- and was reverted per its
// pre-commitment). MFMA recurrence, bank-free HPAD layout, 2 MFMA chains,
// epoch-in-mantissa L3 ring poll, distributed epilogue, 1 barrier/step.
// ---------------------------------------------------------------------------
#define PB4(i) "+v"(Bfrag[(i)+0]), "+v"(Bfrag[(i)+1]), "+v"(Bfrag[(i)+2]), "+v"(Bfrag[(i)+3])

__global__ __launch_bounds__(512, 2) void mgu_rec(
    const float* __restrict__ Whh, const float* __restrict__ bhh,
    float* __restrict__ io, float* __restrict__ hbuf)
{
    const int bid = blockIdx.x;
    const int s   = bid >> 5;     // row slice 0..7 (owns h-rows 64s..64s+64)
    const int g   = bid & 31;     // batch group 0..31
    const int c0  = g * 2;
    const int tid = threadIdx.x;
    const int w   = tid >> 6;     // wave 0..7
    const int l   = tid & 63;
    const int n   = l & 15;       // B col within tile / D col
    const int q   = l >> 4;       // k-subgroup (8 bf16 each)

    __shared__ short hstb[2][2][HPAD];   // [parity][batch][k] bf16, padded
    __shared__ float lds_pad[20480];     // 80 KB -> 1 WG/CU
    if (tid == 0) { volatile float* vp = lds_pad; vp[0] = 0.f; }

    // --- persistent W as B-fragments: B[k][col] = Whh[gaterow(col)][k] ---
    bf16x8 Bfrag[16];
    {
        const int grow = (n < 8) ? (s * 64 + 8 * w + n)
                                 : (512 + s * 64 + 8 * w + (n - 8));
        const float* src = &Whh[(size_t)grow * HH + 8 * q];
        #pragma unroll
        for (int kk = 0; kk < 16; ++kk) {
            bf16x8 f;
            #pragma unroll
            for (int j = 0; j < 8; ++j)
                f[j] = (short)f2bf(src[32 * kk + j]);
            Bfrag[kk] = f;
        }
    }
    asm volatile("" : PB4(0), PB4(4), PB4(8), PB4(12));   // pin

    // epilogue role: lanes 0..7 of wave w own h-row 64s + 8w + l, both batches
    const bool epi = (l < 8);
    float bfv = 0.f, bnv = 0.f, hprev0 = 0.f, hprev1 = 0.f;
    float in_c0 = 0.f, in_c1 = 0.f, in_n0 = 0.f, in_n1 = 0.f;
    size_t ob0 = 0, ob1 = 0;
    if (epi) {
        const int row = s * 64 + 8 * w + l;
        bfv = bhh[row];
        bnv = bhh[512 + row];
        ob0 = (size_t)(c0 + 0) * HH + row;
        ob1 = (size_t)(c0 + 1) * HH + row;
        in_n0 = io[ob0];            // i_n for t=0
        in_n1 = io[ob1];
    }

    const int kb = w * 64;   // poll slice base (k-dimension)

    for (int t = 0; t < TT; ++t) {
        const int par = t & 1;
        in_c0 = in_n0; in_c1 = in_n1;

        // ---- epoch-in-mantissa data poll for own k-slice of h_{t-1} ----
        float v0, v1;
        if (t > 0) {
            const int tr      = t - 1;
            const int slot_r  = tr & 3;
            const unsigned ep = (unsigned)(((tr >> 2) % 3) + 1);
            const float* b0 = &hbuf[(size_t)slot_r * BB * HH
                                    + (size_t)c0 * HH + kb + l];
            const float* b1 = b0 + HH;
            for (;;) {
                v0 = __hip_atomic_load(b0, __ATOMIC_RELAXED, __HIP_MEMORY_SCOPE_AGENT);
                v1 = __hip_atomic_load(b1, __ATOMIC_RELAXED, __HIP_MEMORY_SCOPE_AGENT);
                bool ok = ((__float_as_uint(v0) & 3u) == ep) &&
                          ((__float_as_uint(v1) & 3u) == ep);
                if (__all(ok)) break;
            }
        } else {
            v0 = 0.f; v1 = 0.f;
        }
        // stage bf16 h (epoch bits vanish below bf16 precision)
        hstb[par][0][kb + l] = (short)f2bf(v0);
        hstb[par][1][kb + l] = (short)f2bf(v1);

        // prefetch i_n for t+1 (hidden under barrier + MFMA)
        if (epi && t + 1 < TT) {
            in_n0 = io[ob0 + (size_t)(t + 1) * BB * HH];
            in_n1 = io[ob1 + (size_t)(t + 1) * BB * HH];
        }

        __syncthreads();   // stage visible to all waves (the only barrier)

        // ---- 16 MFMAs in TWO chains (even/odd kk) ----
        f32x4 accE = {0.f, 0.f, 0.f, 0.f};
        f32x4 accO = {0.f, 0.f, 0.f, 0.f};
        const short* abase = &hstb[par][l & 1][8 * q];
        #pragma unroll
        for (int kk = 0; kk < 8; ++kk) {
            bf16x8 aE = *(const bf16x8*)&abase[64 * kk];
            bf16x8 aO = *(const bf16x8*)&abase[64 * kk + 32];
            accE = __builtin_amdgcn_mfma_f32_16x16x32_bf16(aE, Bfrag[2*kk+0], accE, 0, 0, 0);
            accO = __builtin_amdgcn_mfma_f32_16x16x32_bf16(aO, Bfrag[2*kk+1], accO, 0, 0, 0);
        }
        // D layout: col = l&15, row = (l>>4)*4 + reg; reg0/reg1 = batch0/1.
        const float fOwn0 = accE[0] + accO[0];
        const float fOwn1 = accE[1] + accO[1];
        const float oth0 = __shfl_xor(fOwn0, 8, 64);   // partner col c^8
        const float oth1 = __shfl_xor(fOwn1, 8, 64);

        // ---- distributed epilogue: lanes 0..7 (f-cols) of every wave ----
        if (epi) {
            float fg0 = __builtin_amdgcn_rcpf(1.f + __expf(-(fOwn0 + bfv)));
            float e20 = __expf(2.f * (in_c0 + fg0 * (oth0 + bnv)));
            float nv0 = 1.f - 2.f * __builtin_amdgcn_rcpf(e20 + 1.f);
            float hn0 = nv0 + (1.f - fg0) * (hprev0 - nv0);
            float fg1 = __builtin_amdgcn_rcpf(1.f + __expf(-(fOwn1 + bfv)));
            float e21 = __expf(2.f * (in_c1 + fg1 * (oth1 + bnv)));
            float nv1 = 1.f - 2.f * __builtin_amdgcn_rcpf(e21 + 1.f);
            float hn1 = nv1 + (1.f - fg1) * (hprev1 - nv1);
            hprev0 = hn0; hprev1 = hn1;

            // publish epoch-encoded h FIRST (critical path), io after
            const unsigned ep = (unsigned)(((t >> 2) % 3) + 1);
            float ev0 = __uint_as_float((__float_as_uint(hn0) & ~3u) | ep);
            float ev1 = __uint_as_float((__float_as_uint(hn1) & ~3u) | ep);
            const size_t doff = (size_t)(t & 3) * BB * HH;
            __hip_atomic_store(&hbuf[doff + ob0], ev0, __ATOMIC_RELAXED,
                               __HIP_MEMORY_SCOPE_AGENT);
            __hip_atomic_store(&hbuf[doff + ob1], ev1, __ATOMIC_RELAXED,
                               __HIP_MEMORY_SCOPE_AGENT);
            io[ob0 + (size_t)t * BB * HH] = hn0;
            io[ob1 + (size_t)t * BB * HH] = hn1;
        }
        // no trailing barrier: hstb parity-buffered; step barrier bounds skew
    }
}

// ---------------------------------------------------------------------------
extern "C" void kernel_launch(void* const* d_in, const int* in_sizes, int n_in,
                              void* d_out, int out_size, void* d_ws, size_t ws_size,
                              hipStream_t stream)
{
    const float* x   = (const float*)d_in[0];
    const float* Wih = (const float*)d_in[1];
    const float* Whh = (const float*)d_in[2];
    const float* bih = (const float*)d_in[3];
    const float* bhh = (const float*)d_in[4];
    float* io = (float*)d_out;

    float* hbuf = (float*)d_ws;   // 4 slots x 64 batches x 512 f32 = 512 KB

    // zero the slot ring: epoch bits 0 never match live epochs {1,2,3};
    // re-runs every launch/replay -> deterministic.
    (void)hipMemsetAsync(d_ws, 0, 4 * BB * HH * 4, stream);

    in_gemm<<<dim3(2048), dim3(256), 0, stream>>>(x, Wih, bih, io);
    mgu_rec<<<dim3(256), dim3(512), 0, stream>>>(Whh, bhh, io, hbuf);
}

// Round 20
// 1406.268 us; speedup vs baseline: 1.5906x; 1.0188x over previous
//
#include <hip/hip_runtime.h>

#define TT 1024
#define BB 64
#define FF 256
#define HH 512
#define HPAD 544   // batch stride in shorts: 1088B == 64B mod 128B -> bank-free A-reads

typedef short bf16x8 __attribute__((ext_vector_type(8)));
typedef float f32x4  __attribute__((ext_vector_type(4)));

__device__ __forceinline__ unsigned short f2bf(float x) {
    unsigned u = __float_as_uint(x);
    return (unsigned short)((u + 0x7FFFu + ((u >> 16) & 1u)) >> 16);  // RNE
}
__device__ __forceinline__ float bf2f(unsigned short h) {
    return __uint_as_float(((unsigned)h) << 16);
}

// ---------------------------------------------------------------------------
// Kernel 0 (ROUND-20): one-time Wih -> bf16 hi/lo split into d_ws.
// r19's in_gemm had every one of 2048 WGs re-convert the whole 512x256 Wih
// (~1500 VALU ops/thread of redundant conversion -- the reason it ran 155us
// vs the ~30us memory floor). Hoisted here: 131072 elems, ~3us.
// ---------------------------------------------------------------------------
__global__ __launch_bounds__(256) void wconv(
    const float* __restrict__ Wih, short* __restrict__ whi,
    short* __restrict__ wlo)
{
    const int n = HH * FF;  // 131072
    for (int i = blockIdx.x * 256 + threadIdx.x; i < n; i += 128 * 256) {
        float v = Wih[i];
        unsigned short hb = f2bf(v);
        whi[i] = (short)hb;
        wlo[i] = (short)f2bf(v - bf2f(hb));
    }
}

// ---------------------------------------------------------------------------
// Kernel 1 (r19 structure): i_n = x @ Wih^T + bih on the matrix pipe.
// 3-product hi/lo split (fp32-equivalent); B fragments now LOADED as bf16
// from the precomputed whi/wlo (512KB, L2/L3-resident, shared by all WGs)
// -- B-side conversion VALU gone. A-side (x) conversion stays in-kernel
// (per-WG-unique rows). Fragment mapping as verified in r16/r17.
// ---------------------------------------------------------------------------
__global__ __launch_bounds__(256) void in_gemm(
    const float* __restrict__ x, const short* __restrict__ whi,
    const short* __restrict__ wlo, const float* __restrict__ bih,
    float* __restrict__ io)
{
    const int m0   = blockIdx.x * 32;
    const int tid  = threadIdx.x;
    const int w    = tid >> 6;
    const int l    = tid & 63;
    const int rowA = l & 15;        // A-row / B-col / D-col index
    const int koff = 8 * (l >> 4);  // k-offset within each 32-chunk

    f32x4 acc[2][8];
    #pragma unroll
    for (int mt = 0; mt < 2; ++mt)
        #pragma unroll
        for (int nt = 0; nt < 8; ++nt)
            acc[mt][nt] = (f32x4){0.f, 0.f, 0.f, 0.f};

    #pragma unroll 1
    for (int kk = 0; kk < 8; ++kk) {
        // ---- A fragments (x), hi+lo (per-WG-unique -> convert in-kernel) ----
        bf16x8 Ahi[2], Alo[2];
        #pragma unroll
        for (int mt = 0; mt < 2; ++mt) {
            const float* ax = &x[(size_t)(m0 + mt * 16 + rowA) * FF + 32 * kk + koff];
            float4 a0 = *(const float4*)&ax[0];
            float4 a1 = *(const float4*)&ax[4];
            float av[8] = {a0.x, a0.y, a0.z, a0.w, a1.x, a1.y, a1.z, a1.w};
            bf16x8 h, lo;
            #pragma unroll
            for (int j = 0; j < 8; ++j) {
                unsigned short hb = f2bf(av[j]);
                h[j]  = (short)hb;
                lo[j] = (short)f2bf(av[j] - bf2f(hb));
            }
            Ahi[mt] = h; Alo[mt] = lo;
        }
        // ---- B fragments: direct bf16 loads from precomputed hi/lo ----
        #pragma unroll
        for (int half = 0; half < 2; ++half) {
            bf16x8 Bhi[4], Blo[4];
            #pragma unroll
            for (int n4 = 0; n4 < 4; ++n4) {
                const int ncol = 128 * w + (half * 4 + n4) * 16 + rowA;
                const size_t boff = (size_t)ncol * FF + 32 * kk + koff;
                Bhi[n4] = *(const bf16x8*)&whi[boff];
                Blo[n4] = *(const bf16x8*)&wlo[boff];
            }
            #pragma unroll
            for (int mt = 0; mt < 2; ++mt)
                #pragma unroll
                for (int n4 = 0; n4 < 4; ++n4) {
                    const int nt = half * 4 + n4;
                    f32x4 a = acc[mt][nt];
                    a = __builtin_amdgcn_mfma_f32_16x16x32_bf16(Ahi[mt], Bhi[n4], a, 0, 0, 0);
                    a = __builtin_amdgcn_mfma_f32_16x16x32_bf16(Alo[mt], Bhi[n4], a, 0, 0, 0);
                    a = __builtin_amdgcn_mfma_f32_16x16x32_bf16(Ahi[mt], Blo[n4], a, 0, 0, 0);
                    acc[mt][nt] = a;
                }
        }
    }

    // ---- epilogue: D col=rowA, row=4*(l>>4)+r ----
    #pragma unroll
    for (int nt = 0; nt < 8; ++nt) {
        const int col = 128 * w + nt * 16 + rowA;
        const float bv = bih[col];
        #pragma unroll
        for (int mt = 0; mt < 2; ++mt) {
            #pragma unroll
            for (int r = 0; r < 4; ++r) {
                const int row = m0 + mt * 16 + (l >> 4) * 4 + r;
                io[(size_t)row * HH + col] = acc[mt][nt][r] + bv;
            }
        }
    }
}

// ---------------------------------------------------------------------------
// Kernel 2: ROUND-17 VERBATIM (protocol floor: 1277us). MFMA recurrence,
// bank-free HPAD layout, 2 MFMA chains, epoch-in-mantissa L3 ring poll,
// distributed epilogue, 1 barrier/step. r10/r15/r18 all failed to hide the
// L3 exchange RTT further; accepted as the latency floor of this protocol.
// ---------------------------------------------------------------------------
#define PB4(i) "+v"(Bfrag[(i)+0]), "+v"(Bfrag[(i)+1]), "+v"(Bfrag[(i)+2]), "+v"(Bfrag[(i)+3])

__global__ __launch_bounds__(512, 2) void mgu_rec(
    const float* __restrict__ Whh, const float* __restrict__ bhh,
    float* __restrict__ io, float* __restrict__ hbuf)
{
    const int bid = blockIdx.x;
    const int s   = bid >> 5;     // row slice 0..7 (owns h-rows 64s..64s+64)
    const int g   = bid & 31;     // batch group 0..31
    const int c0  = g * 2;
    const int tid = threadIdx.x;
    const int w   = tid >> 6;     // wave 0..7
    const int l   = tid & 63;
    const int n   = l & 15;       // B col within tile / D col
    const int q   = l >> 4;       // k-subgroup (8 bf16 each)

    __shared__ short hstb[2][2][HPAD];   // [parity][batch][k] bf16, padded
    __shared__ float lds_pad[20480];     // 80 KB -> 1 WG/CU
    if (tid == 0) { volatile float* vp = lds_pad; vp[0] = 0.f; }

    // --- persistent W as B-fragments: B[k][col] = Whh[gaterow(col)][k] ---
    bf16x8 Bfrag[16];
    {
        const int grow = (n < 8) ? (s * 64 + 8 * w + n)
                                 : (512 + s * 64 + 8 * w + (n - 8));
        const float* src = &Whh[(size_t)grow * HH + 8 * q];
        #pragma unroll
        for (int kk = 0; kk < 16; ++kk) {
            bf16x8 f;
            #pragma unroll
            for (int j = 0; j < 8; ++j)
                f[j] = (short)f2bf(src[32 * kk + j]);
            Bfrag[kk] = f;
        }
    }
    asm volatile("" : PB4(0), PB4(4), PB4(8), PB4(12));   // pin

    // epilogue role: lanes 0..7 of wave w own h-row 64s + 8w + l, both batches
    const bool epi = (l < 8);
    float bfv = 0.f, bnv = 0.f, hprev0 = 0.f, hprev1 = 0.f;
    float in_c0 = 0.f, in_c1 = 0.f, in_n0 = 0.f, in_n1 = 0.f;
    size_t ob0 = 0, ob1 = 0;
    if (epi) {
        const int row = s * 64 + 8 * w + l;
        bfv = bhh[row];
        bnv = bhh[512 + row];
        ob0 = (size_t)(c0 + 0) * HH + row;
        ob1 = (size_t)(c0 + 1) * HH + row;
        in_n0 = io[ob0];            // i_n for t=0
        in_n1 = io[ob1];
    }

    const int kb = w * 64;   // poll slice base (k-dimension)

    for (int t = 0; t < TT; ++t) {
        const int par = t & 1;
        in_c0 = in_n0; in_c1 = in_n1;

        // ---- epoch-in-mantissa data poll for own k-slice of h_{t-1} ----
        float v0, v1;
        if (t > 0) {
            const int tr      = t - 1;
            const int slot_r  = tr & 3;
            const unsigned ep = (unsigned)(((tr >> 2) % 3) + 1);
            const float* b0 = &hbuf[(size_t)slot_r * BB * HH
                                    + (size_t)c0 * HH + kb + l];
            const float* b1 = b0 + HH;
            for (;;) {
                v0 = __hip_atomic_load(b0, __ATOMIC_RELAXED, __HIP_MEMORY_SCOPE_AGENT);
                v1 = __hip_atomic_load(b1, __ATOMIC_RELAXED, __HIP_MEMORY_SCOPE_AGENT);
                bool ok = ((__float_as_uint(v0) & 3u) == ep) &&
                          ((__float_as_uint(v1) & 3u) == ep);
                if (__all(ok)) break;
            }
        } else {
            v0 = 0.f; v1 = 0.f;
        }
        // stage bf16 h (epoch bits vanish below bf16 precision)
        hstb[par][0][kb + l] = (short)f2bf(v0);
        hstb[par][1][kb + l] = (short)f2bf(v1);

        // prefetch i_n for t+1 (hidden under barrier + MFMA)
        if (epi && t + 1 < TT) {
            in_n0 = io[ob0 + (size_t)(t + 1) * BB * HH];
            in_n1 = io[ob1 + (size_t)(t + 1) * BB * HH];
        }

        __syncthreads();   // stage visible to all waves (the only barrier)

        // ---- 16 MFMAs in TWO chains (even/odd kk) ----
        f32x4 accE = {0.f, 0.f, 0.f, 0.f};
        f32x4 accO = {0.f, 0.f, 0.f, 0.f};
        const short* abase = &hstb[par][l & 1][8 * q];
        #pragma unroll
        for (int kk = 0; kk < 8; ++kk) {
            bf16x8 aE = *(const bf16x8*)&abase[64 * kk];
            bf16x8 aO = *(const bf16x8*)&abase[64 * kk + 32];
            accE = __builtin_amdgcn_mfma_f32_16x16x32_bf16(aE, Bfrag[2*kk+0], accE, 0, 0, 0);
            accO = __builtin_amdgcn_mfma_f32_16x16x32_bf16(aO, Bfrag[2*kk+1], accO, 0, 0, 0);
        }
        // D layout: col = l&15, row = (l>>4)*4 + reg; reg0/reg1 = batch0/1.
        const float fOwn0 = accE[0] + accO[0];
        const float fOwn1 = accE[1] + accO[1];
        const float oth0 = __shfl_xor(fOwn0, 8, 64);   // partner col c^8
        const float oth1 = __shfl_xor(fOwn1, 8, 64);

        // ---- distributed epilogue: lanes 0..7 (f-cols) of every wave ----
        if (epi) {
            float fg0 = __builtin_amdgcn_rcpf(1.f + __expf(-(fOwn0 + bfv)));
            float e20 = __expf(2.f * (in_c0 + fg0 * (oth0 + bnv)));
            float nv0 = 1.f - 2.f * __builtin_amdgcn_rcpf(e20 + 1.f);
            float hn0 = nv0 + (1.f - fg0) * (hprev0 - nv0);
            float fg1 = __builtin_amdgcn_rcpf(1.f + __expf(-(fOwn1 + bfv)));
            float e21 = __expf(2.f * (in_c1 + fg1 * (oth1 + bnv)));
            float nv1 = 1.f - 2.f * __builtin_amdgcn_rcpf(e21 + 1.f);
            float hn1 = nv1 + (1.f - fg1) * (hprev1 - nv1);
            hprev0 = hn0; hprev1 = hn1;

            // publish epoch-encoded h FIRST (critical path), io after
            const unsigned ep = (unsigned)(((t >> 2) % 3) + 1);
            float ev0 = __uint_as_float((__float_as_uint(hn0) & ~3u) | ep);
            float ev1 = __uint_as_float((__float_as_uint(hn1) & ~3u) | ep);
            const size_t doff = (size_t)(t & 3) * BB * HH;
            __hip_atomic_store(&hbuf[doff + ob0], ev0, __ATOMIC_RELAXED,
                               __HIP_MEMORY_SCOPE_AGENT);
            __hip_atomic_store(&hbuf[doff + ob1], ev1, __ATOMIC_RELAXED,
                               __HIP_MEMORY_SCOPE_AGENT);
            io[ob0 + (size_t)t * BB * HH] = hn0;
            io[ob1 + (size_t)t * BB * HH] = hn1;
        }
        // no trailing barrier: hstb parity-buffered; step barrier bounds skew
    }
}

// ---------------------------------------------------------------------------
extern "C" void kernel_launch(void* const* d_in, const int* in_sizes, int n_in,
                              void* d_out, int out_size, void* d_ws, size_t ws_size,
                              hipStream_t stream)
{
    const float* x   = (const float*)d_in[0];
    const float* Wih = (const float*)d_in[1];
    const float* Whh = (const float*)d_in[2];
    const float* bih = (const float*)d_in[3];
    const float* bhh = (const float*)d_in[4];
    float* io = (float*)d_out;

    // d_ws layout: [0,512K) h slot ring | [512K,768K) whi | [768K,1M) wlo
    float* hbuf = (float*)d_ws;
    short* whi  = (short*)((char*)d_ws + 512 * 1024);
    short* wlo  = (short*)((char*)d_ws + 768 * 1024);

    // zero the slot ring: epoch bits 0 never match live epochs {1,2,3};
    // re-runs every launch/replay -> deterministic. whi/wlo are fully
    // overwritten by wconv each launch (no zeroing needed).
    (void)hipMemsetAsync(d_ws, 0, 512 * 1024, stream);

    wconv<<<dim3(128), dim3(256), 0, stream>>>(Wih, whi, wlo);
    in_gemm<<<dim3(2048), dim3(256), 0, stream>>>(x, whi, wlo, bih, io);
    mgu_rec<<<dim3(256), dim3(512), 0, stream>>>(Whh, bhh, io, hbuf);
}